// Round 1
// 280.266 us; speedup vs baseline: 1.0680x; 1.0680x over previous
//
#include <hip/hip_runtime.h>

// EdgeSageLayer on MI355X — round 8.
// agg[n] = (sum_{e:dst=n} concat(x[src_e], ea_e)) @ msg_w / deg + msg_b*(deg>0)
// R7: single-pass bucket CSR, 2-node/wave aggregate, fused 64-thr finalize.
// R7 postmortem: aggregate_bucket_k is the top dispatch (~70us) and is
// LATENCY-bound: VALUBusy 10%, HBM 27%, occupancy 67%, 0 bank conflicts.
// Cause: x-loop and ea-loop are sequential; each iter's accumulate forces a
// vmcnt wait before the next loads issue -> ~2 loads in flight per wave.
// R8: one fused 16-edge/iter loop, all 12 gathers (8 x + 4 ea across the
// 2-node pair) issued into zero-init masked temps BEFORE accumulation
// (MLP 2 -> ~12). ea + bucket loads nontemporal (read-once streams) so the
// 102 MB ea stream stops evicting the 12.8 MB x array from L2/L3.

constexpr int N_NODES  = 50000;
constexpr int N_EDGES  = 800000;
constexpr int IN_DIM   = 64;
constexpr int EDGE_DIM = 32;
constexpr int OUT_DIM  = 64;
constexpr int CAP      = 48;      // bucket capacity; Poisson(16) max deg ~40
constexpr int OVF_CAP  = 65536;   // overflow list capacity (deg>CAP tails)

using vf4 = __attribute__((ext_vector_type(4))) float;
using vi2 = __attribute__((ext_vector_type(2))) int;

// ---------------------------------------------------------------------------
// K1: single-pass bucket build. pos = atomicAdd(cnt[dst]); write (e,src).
// Rare pos>=CAP goes to the overflow list.
// ---------------------------------------------------------------------------
__device__ __forceinline__ void place_one(int dst, int e, int src,
                                          int* cnt, int2* buckets,
                                          int4* ovf, int* ovf_cur) {
    const int pos = atomicAdd(&cnt[dst], 1);
    if (pos < CAP) {
        buckets[(size_t)dst * CAP + pos] = make_int2(e, src);
    } else {
        const int o = atomicAdd(ovf_cur, 1);
        if (o < OVF_CAP) ovf[o] = make_int4(dst, e, src, 0);
    }
}

__global__ __launch_bounds__(256) void place_bucket_k(
    const int* __restrict__ ei, int* cnt, int2* __restrict__ buckets,
    int4* __restrict__ ovf, int* ovf_cur)
{
    const int t = blockIdx.x * 256 + threadIdx.x;
    if (t * 4 + 3 < N_EDGES) {
        const int4 d4 = ((const int4*)(ei + N_EDGES))[t];
        const int4 s4 = ((const int4*)ei)[t];
        place_one(d4.x, 4 * t + 0, s4.x, cnt, buckets, ovf, ovf_cur);
        place_one(d4.y, 4 * t + 1, s4.y, cnt, buckets, ovf, ovf_cur);
        place_one(d4.z, 4 * t + 2, s4.z, cnt, buckets, ovf, ovf_cur);
        place_one(d4.w, 4 * t + 3, s4.w, cnt, buckets, ovf, ovf_cur);
    } else {
        for (int e = t * 4; e < min(t * 4 + 4, N_EDGES); ++e)
            place_one(ei[N_EDGES + e], e, ei[e], cnt, buckets, ovf, ovf_cur);
    }
}

// ---------------------------------------------------------------------------
// K2: gather-reduce, 2 nodes/wave, R8 deep-MLP inner loop.
// x rows: float4 x 16 lanes (4 edges/instr); ea: float4 x 8 lanes (8/instr).
// 16 edges per iteration: 4 x-loads + 2 ea-loads per node, all issued into
// zero-init masked temps before any accumulate -> 12 loads in flight.
// shfl_xor reduce; float4 stores zero-fill deg==0 rows.
// Nodes with cnt>CAP scan the (tiny) overflow list before the reduce.
// ---------------------------------------------------------------------------
__global__ __launch_bounds__(256) void aggregate_bucket_k(
    const float* __restrict__ x, const float* __restrict__ ea,
    const int2* __restrict__ buckets, const int* __restrict__ cnt,
    const int4* __restrict__ ovf, const int* __restrict__ ovf_cur,
    float* __restrict__ sum_x, float* __restrict__ sum_ea)
{
    const int lane   = threadIdx.x & 63;
    const int wave   = (blockIdx.x * blockDim.x + threadIdx.x) >> 6;
    const int nwaves = (gridDim.x * blockDim.x) >> 6;

    const int grpx = lane >> 4, colx = lane & 15;  // x: 4 edges/step
    const int grpe = lane >> 3, cole = lane & 7;   // ea: 8 edges/step

    for (int n0 = wave * 2; n0 < N_NODES; n0 += nwaves * 2) {
        const int  nA   = __builtin_amdgcn_readfirstlane(n0);
        const bool hasB = (n0 + 1 < N_NODES);
        const int  nB   = nA + 1;

        const int cFA = __builtin_amdgcn_readfirstlane(cnt[nA]);
        const int cFB = hasB ? __builtin_amdgcn_readfirstlane(cnt[nB]) : 0;
        const int cA  = min(cFA, CAP);
        const int cB  = min(cFB, CAP);

        // index batches (<=48 entries, one int2 gather each, parallel chains)
        int eA = 0, srcA = 0, eB = 0, srcB = 0;
        if (lane < cA) {
            const vi2 p = __builtin_nontemporal_load(
                (const vi2*)buckets + (size_t)nA * CAP + lane);
            eA = p.x; srcA = p.y;
        }
        if (lane < cB) {
            const vi2 p = __builtin_nontemporal_load(
                (const vi2*)buckets + (size_t)nB * CAP + lane);
            eB = p.x; srcB = p.y;
        }

        vf4 axA = {0,0,0,0}, aeA = {0,0,0,0};
        vf4 axB = {0,0,0,0}, aeB = {0,0,0,0};

        const int mMax = max(cA, cB);
        for (int j = 0; j < mMax; j += 16) {
            const int jx0 = j +  0 + grpx, jx1 = j +  4 + grpx;
            const int jx2 = j +  8 + grpx, jx3 = j + 12 + grpx;
            const int je0 = j +  0 + grpe, je1 = j +  8 + grpe;
            // max lane index shuffled from: 47 (j<=32, +12+3 / +8+7) < 64. OK.
            // lanes >= cnt hold 0 -> addresses always valid; loads are masked.
            const int sA0 = __shfl(srcA, jx0), sA1 = __shfl(srcA, jx1);
            const int sA2 = __shfl(srcA, jx2), sA3 = __shfl(srcA, jx3);
            const int sB0 = __shfl(srcB, jx0), sB1 = __shfl(srcB, jx1);
            const int sB2 = __shfl(srcB, jx2), sB3 = __shfl(srcB, jx3);
            const int fA0 = __shfl(eA, je0),   fA1 = __shfl(eA, je1);
            const int fB0 = __shfl(eB, je0),   fB1 = __shfl(eB, je1);

            vf4 xA0 = {0,0,0,0}, xA1 = {0,0,0,0}, xA2 = {0,0,0,0}, xA3 = {0,0,0,0};
            vf4 xB0 = {0,0,0,0}, xB1 = {0,0,0,0}, xB2 = {0,0,0,0}, xB3 = {0,0,0,0};
            vf4 eA0v = {0,0,0,0}, eA1v = {0,0,0,0};
            vf4 eB0v = {0,0,0,0}, eB1v = {0,0,0,0};

            // all 12 loads issue before any accumulate (independent temps)
            if (jx0 < cA) xA0 = ((const vf4*)(x + (size_t)sA0 * IN_DIM))[colx];
            if (jx1 < cA) xA1 = ((const vf4*)(x + (size_t)sA1 * IN_DIM))[colx];
            if (jx2 < cA) xA2 = ((const vf4*)(x + (size_t)sA2 * IN_DIM))[colx];
            if (jx3 < cA) xA3 = ((const vf4*)(x + (size_t)sA3 * IN_DIM))[colx];
            if (jx0 < cB) xB0 = ((const vf4*)(x + (size_t)sB0 * IN_DIM))[colx];
            if (jx1 < cB) xB1 = ((const vf4*)(x + (size_t)sB1 * IN_DIM))[colx];
            if (jx2 < cB) xB2 = ((const vf4*)(x + (size_t)sB2 * IN_DIM))[colx];
            if (jx3 < cB) xB3 = ((const vf4*)(x + (size_t)sB3 * IN_DIM))[colx];
            if (je0 < cA) eA0v = __builtin_nontemporal_load(
                (const vf4*)(ea + (size_t)fA0 * EDGE_DIM) + cole);
            if (je1 < cA) eA1v = __builtin_nontemporal_load(
                (const vf4*)(ea + (size_t)fA1 * EDGE_DIM) + cole);
            if (je0 < cB) eB0v = __builtin_nontemporal_load(
                (const vf4*)(ea + (size_t)fB0 * EDGE_DIM) + cole);
            if (je1 < cB) eB1v = __builtin_nontemporal_load(
                (const vf4*)(ea + (size_t)fB1 * EDGE_DIM) + cole);

            axA += (xA0 + xA1) + (xA2 + xA3);
            axB += (xB0 + xB1) + (xB2 + xB3);
            aeA += eA0v + eA1v;
            aeB += eB0v + eB1v;
        }

        // rare: overflow entries (deg > CAP). Group 0 accumulates pre-reduce.
        if (cFA > CAP || cFB > CAP) {
            const int novf = min(__builtin_amdgcn_readfirstlane(*ovf_cur), OVF_CAP);
            for (int i = 0; i < novf; ++i) {
                const int4 v = ovf[i];
                const bool mA = (v.x == nA), mB = hasB && (v.x == nB);
                if (mA || mB) {
                    if (grpx == 0) {
                        const vf4 t = ((const vf4*)(x + (size_t)v.z * IN_DIM))[colx];
                        if (mA) axA += t; else axB += t;
                    }
                    if (grpe == 0) {
                        const vf4 t = ((const vf4*)(ea + (size_t)v.y * EDGE_DIM))[cole];
                        if (mA) aeA += t; else aeB += t;
                    }
                }
            }
        }

#pragma unroll
        for (int mask = 16; mask < 64; mask <<= 1) {
            axA.x += __shfl_xor(axA.x, mask); axA.y += __shfl_xor(axA.y, mask);
            axA.z += __shfl_xor(axA.z, mask); axA.w += __shfl_xor(axA.w, mask);
            axB.x += __shfl_xor(axB.x, mask); axB.y += __shfl_xor(axB.y, mask);
            axB.z += __shfl_xor(axB.z, mask); axB.w += __shfl_xor(axB.w, mask);
        }
#pragma unroll
        for (int mask = 8; mask < 64; mask <<= 1) {
            aeA.x += __shfl_xor(aeA.x, mask); aeA.y += __shfl_xor(aeA.y, mask);
            aeA.z += __shfl_xor(aeA.z, mask); aeA.w += __shfl_xor(aeA.w, mask);
            aeB.x += __shfl_xor(aeB.x, mask); aeB.y += __shfl_xor(aeB.y, mask);
            aeB.z += __shfl_xor(aeB.z, mask); aeB.w += __shfl_xor(aeB.w, mask);
        }

        if (lane < 16) ((vf4*)(sum_x + (size_t)nA * IN_DIM))[lane] = axA;
        if (lane < 8)  ((vf4*)(sum_ea + (size_t)nA * EDGE_DIM))[lane] = aeA;
        if (hasB) {
            if (lane < 16) ((vf4*)(sum_x + (size_t)nB * IN_DIM))[lane] = axB;
            if (lane < 8)  ((vf4*)(sum_ea + (size_t)nB * EDGE_DIM))[lane] = aeB;
        }
    }
}

// ---------------------------------------------------------------------------
// K3: fused finalize. 64-thread blocks = 1 wave/block -> VGPR budget up to
// ~256+, so all 96+64 weight floats stay resident (256-thr version remat'd
// at VGPR=124, R4). Lane c owns output column c.
// sum_x_in aliases out; each row touched by exactly one wave.
// ---------------------------------------------------------------------------
__global__ __launch_bounds__(64) void finalize64_k(
    const float* __restrict__ x, const float* sum_x_in,
    const float* __restrict__ sum_ea, const int* __restrict__ cnt,
    const float* __restrict__ msg_w, const float* __restrict__ msg_b,
    const float* __restrict__ self_w, const float* __restrict__ self_b,
    float* out)
{
    const int c = threadIdx.x;  // 0..63

    float wm[96];   // msg_w column c
    float wsf[64];  // self_w column c
#pragma unroll
    for (int k = 0; k < 96; ++k) wm[k] = msg_w[k * OUT_DIM + c];
#pragma unroll
    for (int k = 0; k < 64; ++k) wsf[k] = self_w[k * OUT_DIM + c];
    const float mb = msg_b[c];
    const float sb = self_b[c];

    for (int n0 = blockIdx.x; n0 < N_NODES; n0 += gridDim.x) {
        const int n = __builtin_amdgcn_readfirstlane(n0);

        const float4* r1 = (const float4*)(sum_x_in + (size_t)n * IN_DIM);
        const float4* r2 = (const float4*)(sum_ea   + (size_t)n * EDGE_DIM);
        const float4* r3 = (const float4*)(x        + (size_t)n * IN_DIM);
        const int d = cnt[n];

        float am0 = 0.f, am1 = 0.f, am2 = 0.f, am3 = 0.f;
        float as0 = 0.f, as1 = 0.f, as2 = 0.f, as3 = 0.f;
#pragma unroll
        for (int q = 0; q < 16; ++q) {
            const float4 v = r1[q];
            am0 = fmaf(v.x, wm[4 * q + 0], am0);
            am1 = fmaf(v.y, wm[4 * q + 1], am1);
            am2 = fmaf(v.z, wm[4 * q + 2], am2);
            am3 = fmaf(v.w, wm[4 * q + 3], am3);
        }
#pragma unroll
        for (int q = 0; q < 8; ++q) {
            const float4 v = r2[q];
            am0 = fmaf(v.x, wm[64 + 4 * q + 0], am0);
            am1 = fmaf(v.y, wm[64 + 4 * q + 1], am1);
            am2 = fmaf(v.z, wm[64 + 4 * q + 2], am2);
            am3 = fmaf(v.w, wm[64 + 4 * q + 3], am3);
        }
#pragma unroll
        for (int q = 0; q < 16; ++q) {
            const float4 v = r3[q];
            as0 = fmaf(v.x, wsf[4 * q + 0], as0);
            as1 = fmaf(v.y, wsf[4 * q + 1], as1);
            as2 = fmaf(v.z, wsf[4 * q + 2], as2);
            as3 = fmaf(v.w, wsf[4 * q + 3], as3);
        }

        const float inv  = 1.0f / (float)max(d, 1);
        const float bsel = (d > 0) ? 1.0f : 0.0f;
        const float am   = (am0 + am1) + (am2 + am3);
        const float as   = (as0 + as1) + (as2 + as3);

        out[(size_t)n * OUT_DIM + c] = as + sb + am * inv + mb * bsel;
    }
}

// ---------------------------------------------------------------------------
// Tier-3 fallback: atomic scatter (needs only ~6.6 MB ws).
// ---------------------------------------------------------------------------
__global__ __launch_bounds__(768) void scatter_fb_k(
    const float* __restrict__ x, const int* __restrict__ ei,
    const float* __restrict__ ea, float* sum_x, float* sum_ea, int* deg)
{
    const int t  = threadIdx.x;
    const int el = t / 96;
    const int k  = t - el * 96;
    const int e  = blockIdx.x * 8 + el;
    if (e >= N_EDGES) return;
    const int dst = ei[N_EDGES + e];
    if (k < IN_DIM) {
        const int src = ei[e];
        atomicAdd(&sum_x[dst * IN_DIM + k], x[src * IN_DIM + k]);
        if (k == 0) atomicAdd(&deg[dst], 1);
    } else {
        const int kk = k - IN_DIM;
        atomicAdd(&sum_ea[dst * EDGE_DIM + kk], ea[e * EDGE_DIM + kk]);
    }
}

// ---------------------------------------------------------------------------
extern "C" void kernel_launch(void* const* d_in, const int* in_sizes, int n_in,
                              void* d_out, int out_size, void* d_ws, size_t ws_size,
                              hipStream_t stream) {
    const float* x      = (const float*)d_in[0];
    const int*   ei     = (const int*)d_in[1];   // [2][E]
    const float* ea     = (const float*)d_in[2];
    const float* msg_w  = (const float*)d_in[3];
    const float* msg_b  = (const float*)d_in[4];
    const float* self_w = (const float*)d_in[5];
    const float* self_b = (const float*)d_in[6];

    float* out = (float*)d_out;  // doubles as sum_x accumulator

    // ws layout (ints unless noted):
    //   cnt[50000] | ovf_cur[1] | pad to 16 | buckets[50000*CAP int2]
    //   | ovf[OVF_CAP int4] | sum_ea[1.6M float]
    int*   cnt     = (int*)d_ws;
    int*   ovf_cur = cnt + N_NODES;
    int2*  buckets = (int2*)(cnt + N_NODES + 16);
    int4*  ovf     = (int4*)(buckets + (size_t)N_NODES * CAP);
    float* sum_ea  = (float*)(ovf + OVF_CAP);
    const size_t need_bucket =
        ((size_t)N_NODES + 16 + 2 * (size_t)N_NODES * CAP + 4 * (size_t)OVF_CAP +
         (size_t)N_NODES * EDGE_DIM) * sizeof(int);

    if (ws_size >= need_bucket) {
        hipMemsetAsync(cnt, 0, (N_NODES + 16) * sizeof(int), stream);
        place_bucket_k<<<(N_EDGES / 4 + 255) / 256, 256, 0, stream>>>(
            ei, cnt, buckets, ovf, ovf_cur);
        aggregate_bucket_k<<<(N_NODES / 2 + 3) / 4, 256, 0, stream>>>(
            x, ea, buckets, cnt, ovf, ovf_cur, out, sum_ea);
        finalize64_k<<<4096, 64, 0, stream>>>(
            x, out, sum_ea, cnt, msg_w, msg_b, self_w, self_b, out);
    } else {
        // Fallback: fp32 atomic scatter (R1 path) + fused finalize
        float* fb_sum_ea = (float*)d_ws;
        int*   deg       = (int*)(fb_sum_ea + (size_t)N_NODES * EDGE_DIM);
        hipMemsetAsync(d_out, 0, (size_t)N_NODES * OUT_DIM * sizeof(float), stream);
        hipMemsetAsync(d_ws, 0, (size_t)N_NODES * (EDGE_DIM + 1) * sizeof(float), stream);
        scatter_fb_k<<<(N_EDGES + 7) / 8, 768, 0, stream>>>(
            x, ei, ea, out, fb_sum_ea, deg);
        finalize64_k<<<4096, 64, 0, stream>>>(
            x, out, fb_sum_ea, deg, msg_w, msg_b, self_w, self_b, out);
    }
}

// Round 2
// 274.401 us; speedup vs baseline: 1.0908x; 1.0214x over previous
//
#include <hip/hip_runtime.h>

// EdgeSageLayer on MI355X — round 9.
// agg[n] = (sum_{e:dst=n} concat(x[src_e], ea_e)) @ msg_w / deg + msg_b*(deg>0)
// R8: deep-MLP gather (12 loads in flight) took aggregate 70 -> ~50us;
// total 299 -> 280 (delta == aggregate delta; rest unchanged).
// R8 postmortem: top-5 is now harness ws-poison fills (61us, untouchable).
// Our ~165us = place (~55) + aggregate (~50) + finalize (~50). finalize is a
// 50000x160 @ 160x64 fp32 matvec with a 13-15us roofline running at ~50us
// (1-wave blocks, 160-load weight preload per 12 nodes, serial chains), while
// aggregate's VALU is 90% idle (VALUBusy 10%).
// R9: DELETE the finalize pass. After the shfl-reduce the wave holds the
// 160-dim concat row in registers; dump it to a 640B per-wave LDS scratch and
// compute all 64 output columns in-kernel against a block-resident weight
// copy (41KB LDS, staged once per 512-thr block). Kills 18.75MB write +
// 45MB read + one latency-bound dispatch; matmul VALU hides under gather
// latency. W-read k*64+c across 64 lanes = 2-way bank alias = free; scratch
// reads are same-address broadcast; one W read feeds both nodes of the pair.

constexpr int N_NODES  = 50000;
constexpr int N_EDGES  = 800000;
constexpr int IN_DIM   = 64;
constexpr int EDGE_DIM = 32;
constexpr int OUT_DIM  = 64;
constexpr int CAP      = 48;      // bucket capacity; Poisson(16) max deg ~40
constexpr int OVF_CAP  = 65536;   // overflow list capacity (deg>CAP tails)

using vf4 = __attribute__((ext_vector_type(4))) float;
using vi2 = __attribute__((ext_vector_type(2))) int;

// ---------------------------------------------------------------------------
// K1: single-pass bucket build. pos = atomicAdd(cnt[dst]); write (e,src).
// Rare pos>=CAP goes to the overflow list.
// ---------------------------------------------------------------------------
__device__ __forceinline__ void place_one(int dst, int e, int src,
                                          int* cnt, int2* buckets,
                                          int4* ovf, int* ovf_cur) {
    const int pos = atomicAdd(&cnt[dst], 1);
    if (pos < CAP) {
        buckets[(size_t)dst * CAP + pos] = make_int2(e, src);
    } else {
        const int o = atomicAdd(ovf_cur, 1);
        if (o < OVF_CAP) ovf[o] = make_int4(dst, e, src, 0);
    }
}

__global__ __launch_bounds__(256) void place_bucket_k(
    const int* __restrict__ ei, int* cnt, int2* __restrict__ buckets,
    int4* __restrict__ ovf, int* ovf_cur)
{
    const int t = blockIdx.x * 256 + threadIdx.x;
    if (t * 4 + 3 < N_EDGES) {
        const int4 d4 = ((const int4*)(ei + N_EDGES))[t];
        const int4 s4 = ((const int4*)ei)[t];
        place_one(d4.x, 4 * t + 0, s4.x, cnt, buckets, ovf, ovf_cur);
        place_one(d4.y, 4 * t + 1, s4.y, cnt, buckets, ovf, ovf_cur);
        place_one(d4.z, 4 * t + 2, s4.z, cnt, buckets, ovf, ovf_cur);
        place_one(d4.w, 4 * t + 3, s4.w, cnt, buckets, ovf, ovf_cur);
    } else {
        for (int e = t * 4; e < min(t * 4 + 4, N_EDGES); ++e)
            place_one(ei[N_EDGES + e], e, ei[e], cnt, buckets, ovf, ovf_cur);
    }
}

// ---------------------------------------------------------------------------
// K2 (R9): fused gather-reduce + output matmul. 512 threads = 8 waves,
// 2 nodes/wave/iter, persistent grid of 768 blocks.
// LDS: weights [160][64] (msg_w rows 0..95, self_w rows 96..159) + biases +
// per-wave [2][160] concat scratch = 51.7 KB -> >=2 blocks/CU.
// ---------------------------------------------------------------------------
__global__ __launch_bounds__(512) void agg_fused_k(
    const float* __restrict__ x, const float* __restrict__ ea,
    const int2* __restrict__ buckets, const int* __restrict__ cnt,
    const int4* __restrict__ ovf, const int* __restrict__ ovf_cur,
    const float* __restrict__ msg_w, const float* __restrict__ msg_b,
    const float* __restrict__ self_w, const float* __restrict__ self_b,
    float* __restrict__ out)
{
    __shared__ float w_lds[160 * 64];   // [k][c]; k<96: msg_w, k>=96: self_w
    __shared__ float b_lds[128];        // [0..63] msg_b, [64..127] self_b
    __shared__ float s_scr[8][2][160];  // [wave][node]{sum_x|sum_ea|x_self}

    const int tid = threadIdx.x;
    // one-time weight stage (coalesced float4)
    for (int i = tid; i < 96 * 64 / 4; i += 512)
        ((vf4*)w_lds)[i] = ((const vf4*)msg_w)[i];
    for (int i = tid; i < 64 * 64 / 4; i += 512)
        ((vf4*)(w_lds + 96 * 64))[i] = ((const vf4*)self_w)[i];
    if (tid < 64)       b_lds[tid] = msg_b[tid];
    else if (tid < 128) b_lds[tid] = self_b[tid - 64];
    __syncthreads();

    const int lane   = tid & 63;
    const int w      = tid >> 6;                       // wave in block
    const int wave   = blockIdx.x * 8 + w;
    const int nwaves = gridDim.x * 8;

    const int grpx = lane >> 4, colx = lane & 15;  // x: 4 edges/step
    const int grpe = lane >> 3, cole = lane & 7;   // ea: 8 edges/step

    const float mb = b_lds[lane];
    const float sb = b_lds[64 + lane];

    for (int n0 = wave * 2; n0 < N_NODES; n0 += nwaves * 2) {
        const int  nA   = __builtin_amdgcn_readfirstlane(n0);
        const bool hasB = (n0 + 1 < N_NODES);
        const int  nB   = nA + 1;

        const int cFA = __builtin_amdgcn_readfirstlane(cnt[nA]);
        const int cFB = hasB ? __builtin_amdgcn_readfirstlane(cnt[nB]) : 0;
        const int cA  = min(cFA, CAP);
        const int cB  = min(cFB, CAP);

        // index batches (<=48 entries, one int2 gather each, parallel chains)
        int eA = 0, srcA = 0, eB = 0, srcB = 0;
        if (lane < cA) {
            const vi2 p = __builtin_nontemporal_load(
                (const vi2*)buckets + (size_t)nA * CAP + lane);
            eA = p.x; srcA = p.y;
        }
        if (lane < cB) {
            const vi2 p = __builtin_nontemporal_load(
                (const vi2*)buckets + (size_t)nB * CAP + lane);
            eB = p.x; srcB = p.y;
        }

        vf4 axA = {0,0,0,0}, aeA = {0,0,0,0};
        vf4 axB = {0,0,0,0}, aeB = {0,0,0,0};

        const int mMax = max(cA, cB);
        for (int j = 0; j < mMax; j += 16) {
            const int jx0 = j +  0 + grpx, jx1 = j +  4 + grpx;
            const int jx2 = j +  8 + grpx, jx3 = j + 12 + grpx;
            const int je0 = j +  0 + grpe, je1 = j +  8 + grpe;
            // max shuffled lane index 47 < 64; lanes >= cnt hold 0 -> valid.
            const int sA0 = __shfl(srcA, jx0), sA1 = __shfl(srcA, jx1);
            const int sA2 = __shfl(srcA, jx2), sA3 = __shfl(srcA, jx3);
            const int sB0 = __shfl(srcB, jx0), sB1 = __shfl(srcB, jx1);
            const int sB2 = __shfl(srcB, jx2), sB3 = __shfl(srcB, jx3);
            const int fA0 = __shfl(eA, je0),   fA1 = __shfl(eA, je1);
            const int fB0 = __shfl(eB, je0),   fB1 = __shfl(eB, je1);

            vf4 xA0 = {0,0,0,0}, xA1 = {0,0,0,0}, xA2 = {0,0,0,0}, xA3 = {0,0,0,0};
            vf4 xB0 = {0,0,0,0}, xB1 = {0,0,0,0}, xB2 = {0,0,0,0}, xB3 = {0,0,0,0};
            vf4 eA0v = {0,0,0,0}, eA1v = {0,0,0,0};
            vf4 eB0v = {0,0,0,0}, eB1v = {0,0,0,0};

            // all 12 loads issue before any accumulate (independent temps)
            if (jx0 < cA) xA0 = ((const vf4*)(x + (size_t)sA0 * IN_DIM))[colx];
            if (jx1 < cA) xA1 = ((const vf4*)(x + (size_t)sA1 * IN_DIM))[colx];
            if (jx2 < cA) xA2 = ((const vf4*)(x + (size_t)sA2 * IN_DIM))[colx];
            if (jx3 < cA) xA3 = ((const vf4*)(x + (size_t)sA3 * IN_DIM))[colx];
            if (jx0 < cB) xB0 = ((const vf4*)(x + (size_t)sB0 * IN_DIM))[colx];
            if (jx1 < cB) xB1 = ((const vf4*)(x + (size_t)sB1 * IN_DIM))[colx];
            if (jx2 < cB) xB2 = ((const vf4*)(x + (size_t)sB2 * IN_DIM))[colx];
            if (jx3 < cB) xB3 = ((const vf4*)(x + (size_t)sB3 * IN_DIM))[colx];
            if (je0 < cA) eA0v = __builtin_nontemporal_load(
                (const vf4*)(ea + (size_t)fA0 * EDGE_DIM) + cole);
            if (je1 < cA) eA1v = __builtin_nontemporal_load(
                (const vf4*)(ea + (size_t)fA1 * EDGE_DIM) + cole);
            if (je0 < cB) eB0v = __builtin_nontemporal_load(
                (const vf4*)(ea + (size_t)fB0 * EDGE_DIM) + cole);
            if (je1 < cB) eB1v = __builtin_nontemporal_load(
                (const vf4*)(ea + (size_t)fB1 * EDGE_DIM) + cole);

            axA += (xA0 + xA1) + (xA2 + xA3);
            axB += (xB0 + xB1) + (xB2 + xB3);
            aeA += eA0v + eA1v;
            aeB += eB0v + eB1v;
        }

        // rare: overflow entries (deg > CAP). Group 0 accumulates pre-reduce.
        if (cFA > CAP || cFB > CAP) {
            const int novf = min(__builtin_amdgcn_readfirstlane(*ovf_cur), OVF_CAP);
            for (int i = 0; i < novf; ++i) {
                const int4 v = ovf[i];
                const bool mA = (v.x == nA), mB = hasB && (v.x == nB);
                if (mA || mB) {
                    if (grpx == 0) {
                        const vf4 t = ((const vf4*)(x + (size_t)v.z * IN_DIM))[colx];
                        if (mA) axA += t; else axB += t;
                    }
                    if (grpe == 0) {
                        const vf4 t = ((const vf4*)(ea + (size_t)v.y * EDGE_DIM))[cole];
                        if (mA) aeA += t; else aeB += t;
                    }
                }
            }
        }

#pragma unroll
        for (int mask = 16; mask < 64; mask <<= 1) {
            axA.x += __shfl_xor(axA.x, mask); axA.y += __shfl_xor(axA.y, mask);
            axA.z += __shfl_xor(axA.z, mask); axA.w += __shfl_xor(axA.w, mask);
            axB.x += __shfl_xor(axB.x, mask); axB.y += __shfl_xor(axB.y, mask);
            axB.z += __shfl_xor(axB.z, mask); axB.w += __shfl_xor(axB.w, mask);
        }
#pragma unroll
        for (int mask = 8; mask < 64; mask <<= 1) {
            aeA.x += __shfl_xor(aeA.x, mask); aeA.y += __shfl_xor(aeA.y, mask);
            aeA.z += __shfl_xor(aeA.z, mask); aeA.w += __shfl_xor(aeA.w, mask);
            aeB.x += __shfl_xor(aeB.x, mask); aeB.y += __shfl_xor(aeB.y, mask);
            aeB.z += __shfl_xor(aeB.z, mask); aeB.w += __shfl_xor(aeB.w, mask);
        }

        // --- fused finalize: scratch = [sum_x(64) | sum_ea(32) | x_self(64)]
        if (lane < 16) {
            *(vf4*)&s_scr[w][0][4 * lane] = axA;
            const vf4 vs = ((const vf4*)(x + (size_t)nA * IN_DIM))[lane];
            *(vf4*)&s_scr[w][0][96 + 4 * lane] = vs;
        }
        if (lane < 8) *(vf4*)&s_scr[w][0][64 + 4 * lane] = aeA;
        if (hasB) {
            if (lane < 16) {
                *(vf4*)&s_scr[w][1][4 * lane] = axB;
                const vf4 vs = ((const vf4*)(x + (size_t)nB * IN_DIM))[lane];
                *(vf4*)&s_scr[w][1][96 + 4 * lane] = vs;
            }
            if (lane < 8) *(vf4*)&s_scr[w][1][64 + 4 * lane] = aeB;
        }
        // lane c computes output column c for both nodes (one W read feeds 2)
        float amA = 0.f, amB = 0.f, asA = 0.f, asB = 0.f;
#pragma unroll 8
        for (int k = 0; k < 96; ++k) {
            const float wv = w_lds[k * 64 + lane];
            amA = fmaf(s_scr[w][0][k], wv, amA);
            amB = fmaf(s_scr[w][1][k], wv, amB);
        }
#pragma unroll 8
        for (int k = 0; k < 64; ++k) {
            const float wv = w_lds[(96 + k) * 64 + lane];
            asA = fmaf(s_scr[w][0][96 + k], wv, asA);
            asB = fmaf(s_scr[w][1][96 + k], wv, asB);
        }
        const float invA = 1.0f / (float)max(cFA, 1);
        const float bselA = (cFA > 0) ? 1.0f : 0.0f;
        out[(size_t)nA * OUT_DIM + lane] = asA + sb + amA * invA + mb * bselA;
        if (hasB) {
            const float invB = 1.0f / (float)max(cFB, 1);
            const float bselB = (cFB > 0) ? 1.0f : 0.0f;
            out[(size_t)nB * OUT_DIM + lane] = asB + sb + amB * invB + mb * bselB;
        }
    }
}

// ---------------------------------------------------------------------------
// K3 (fallback path only): fused finalize, 64-thr blocks.
// ---------------------------------------------------------------------------
__global__ __launch_bounds__(64) void finalize64_k(
    const float* __restrict__ x, const float* sum_x_in,
    const float* __restrict__ sum_ea, const int* __restrict__ cnt,
    const float* __restrict__ msg_w, const float* __restrict__ msg_b,
    const float* __restrict__ self_w, const float* __restrict__ self_b,
    float* out)
{
    const int c = threadIdx.x;  // 0..63

    float wm[96];   // msg_w column c
    float wsf[64];  // self_w column c
#pragma unroll
    for (int k = 0; k < 96; ++k) wm[k] = msg_w[k * OUT_DIM + c];
#pragma unroll
    for (int k = 0; k < 64; ++k) wsf[k] = self_w[k * OUT_DIM + c];
    const float mb = msg_b[c];
    const float sb = self_b[c];

    for (int n0 = blockIdx.x; n0 < N_NODES; n0 += gridDim.x) {
        const int n = __builtin_amdgcn_readfirstlane(n0);

        const float4* r1 = (const float4*)(sum_x_in + (size_t)n * IN_DIM);
        const float4* r2 = (const float4*)(sum_ea   + (size_t)n * EDGE_DIM);
        const float4* r3 = (const float4*)(x        + (size_t)n * IN_DIM);
        const int d = cnt[n];

        float am0 = 0.f, am1 = 0.f, am2 = 0.f, am3 = 0.f;
        float as0 = 0.f, as1 = 0.f, as2 = 0.f, as3 = 0.f;
#pragma unroll
        for (int q = 0; q < 16; ++q) {
            const float4 v = r1[q];
            am0 = fmaf(v.x, wm[4 * q + 0], am0);
            am1 = fmaf(v.y, wm[4 * q + 1], am1);
            am2 = fmaf(v.z, wm[4 * q + 2], am2);
            am3 = fmaf(v.w, wm[4 * q + 3], am3);
        }
#pragma unroll
        for (int q = 0; q < 8; ++q) {
            const float4 v = r2[q];
            am0 = fmaf(v.x, wm[64 + 4 * q + 0], am0);
            am1 = fmaf(v.y, wm[64 + 4 * q + 1], am1);
            am2 = fmaf(v.z, wm[64 + 4 * q + 2], am2);
            am3 = fmaf(v.w, wm[64 + 4 * q + 3], am3);
        }
#pragma unroll
        for (int q = 0; q < 16; ++q) {
            const float4 v = r3[q];
            as0 = fmaf(v.x, wsf[4 * q + 0], as0);
            as1 = fmaf(v.y, wsf[4 * q + 1], as1);
            as2 = fmaf(v.z, wsf[4 * q + 2], as2);
            as3 = fmaf(v.w, wsf[4 * q + 3], as3);
        }

        const float inv  = 1.0f / (float)max(d, 1);
        const float bsel = (d > 0) ? 1.0f : 0.0f;
        const float am   = (am0 + am1) + (am2 + am3);
        const float as   = (as0 + as1) + (as2 + as3);

        out[(size_t)n * OUT_DIM + c] = as + sb + am * inv + mb * bsel;
    }
}

// ---------------------------------------------------------------------------
// Tier-3 fallback: atomic scatter (needs only ~6.6 MB ws).
// ---------------------------------------------------------------------------
__global__ __launch_bounds__(768) void scatter_fb_k(
    const float* __restrict__ x, const int* __restrict__ ei,
    const float* __restrict__ ea, float* sum_x, float* sum_ea, int* deg)
{
    const int t  = threadIdx.x;
    const int el = t / 96;
    const int k  = t - el * 96;
    const int e  = blockIdx.x * 8 + el;
    if (e >= N_EDGES) return;
    const int dst = ei[N_EDGES + e];
    if (k < IN_DIM) {
        const int src = ei[e];
        atomicAdd(&sum_x[dst * IN_DIM + k], x[src * IN_DIM + k]);
        if (k == 0) atomicAdd(&deg[dst], 1);
    } else {
        const int kk = k - IN_DIM;
        atomicAdd(&sum_ea[dst * EDGE_DIM + kk], ea[e * EDGE_DIM + kk]);
    }
}

// ---------------------------------------------------------------------------
extern "C" void kernel_launch(void* const* d_in, const int* in_sizes, int n_in,
                              void* d_out, int out_size, void* d_ws, size_t ws_size,
                              hipStream_t stream) {
    const float* x      = (const float*)d_in[0];
    const int*   ei     = (const int*)d_in[1];   // [2][E]
    const float* ea     = (const float*)d_in[2];
    const float* msg_w  = (const float*)d_in[3];
    const float* msg_b  = (const float*)d_in[4];
    const float* self_w = (const float*)d_in[5];
    const float* self_b = (const float*)d_in[6];

    float* out = (float*)d_out;

    // ws layout (ints unless noted):
    //   cnt[50000] | ovf_cur[1] | pad to 16 | buckets[50000*CAP int2]
    //   | ovf[OVF_CAP int4]
    int*   cnt     = (int*)d_ws;
    int*   ovf_cur = cnt + N_NODES;
    int2*  buckets = (int2*)(cnt + N_NODES + 16);
    int4*  ovf     = (int4*)(buckets + (size_t)N_NODES * CAP);
    const size_t need_bucket =
        ((size_t)N_NODES + 16 + 2 * (size_t)N_NODES * CAP +
         4 * (size_t)OVF_CAP) * sizeof(int);

    if (ws_size >= need_bucket) {
        hipMemsetAsync(cnt, 0, (N_NODES + 16) * sizeof(int), stream);
        place_bucket_k<<<(N_EDGES / 4 + 255) / 256, 256, 0, stream>>>(
            ei, cnt, buckets, ovf, ovf_cur);
        agg_fused_k<<<768, 512, 0, stream>>>(
            x, ea, buckets, cnt, ovf, ovf_cur,
            msg_w, msg_b, self_w, self_b, out);
    } else {
        // Fallback: fp32 atomic scatter (R1 path) + fused finalize
        float* fb_sum_ea = (float*)d_ws;
        int*   deg       = (int*)(fb_sum_ea + (size_t)N_NODES * EDGE_DIM);
        hipMemsetAsync(d_out, 0, (size_t)N_NODES * OUT_DIM * sizeof(float), stream);
        hipMemsetAsync(d_ws, 0, (size_t)N_NODES * (EDGE_DIM + 1) * sizeof(float), stream);
        scatter_fb_k<<<(N_EDGES + 7) / 8, 768, 0, stream>>>(
            x, ei, ea, out, fb_sum_ea, deg);
        finalize64_k<<<4096, 64, 0, stream>>>(
            x, out, fb_sum_ea, deg, msg_w, msg_b, self_w, self_b, out);
    }
}